// Round 1
// baseline (2213.602 us; speedup 1.0000x reference)
//
#include <hip/hip_runtime.h>
#include <math.h>

#define NROWS 8192
#define DIN   512
#define DHID  256
#define DOUT  128

// ---------------------------------------------------------------------------
// Fused MLP GEMM: C = act(A @ W + bias), tile 64x64, micro 4x4, BK=32.
// relu=1 -> ReLU epilogue (GEMM1 -> h). relu=0 -> plain + per-column
// sum/sumsq atomics for the whitening stats (GEMM2 -> y).
// ---------------------------------------------------------------------------
__global__ __launch_bounds__(256) void mlp_gemm_kernel(
    const float* __restrict__ A, int lda, int K,
    const float* __restrict__ W, int ldw,
    const float* __restrict__ bias,
    float* __restrict__ C, int ldc,
    int relu, float* __restrict__ colsum, float* __restrict__ colsumsq)
{
  __shared__ __align__(16) float As[32][68];  // [k][m] transposed
  __shared__ __align__(16) float Bs[32][68];  // [k][n]
  const int tid = threadIdx.x;
  const int tx = tid & 15, ty = tid >> 4;
  const int m0 = blockIdx.x * 64, n0 = blockIdx.y * 64;

  float acc[4][4] = {};

  for (int kk = 0; kk < K; kk += 32) {
#pragma unroll
    for (int i = 0; i < 8; i++) {           // A tile: 64 rows x 32 k
      int e = i * 256 + tid;
      int k = e & 31, m = e >> 5;
      As[k][m] = A[(size_t)(m0 + m) * lda + kk + k];
    }
#pragma unroll
    for (int i = 0; i < 8; i++) {           // W tile: 32 k x 64 n (no transpose)
      int e = i * 256 + tid;
      int j = e & 63, k = e >> 6;
      Bs[k][j] = W[(size_t)(kk + k) * ldw + n0 + j];
    }
    __syncthreads();
#pragma unroll
    for (int k = 0; k < 32; k++) {
      float a[4], b[4];
      *(float4*)&a[0] = *(const float4*)&As[k][ty * 4];
      *(float4*)&b[0] = *(const float4*)&Bs[k][tx * 4];
#pragma unroll
      for (int r = 0; r < 4; r++)
#pragma unroll
        for (int c = 0; c < 4; c++)
          acc[r][c] = fmaf(a[r], b[c], acc[r][c]);
    }
    __syncthreads();
  }

  float bb[4];
  *(float4*)&bb[0] = *(const float4*)&bias[n0 + tx * 4];

  if (relu) {
#pragma unroll
    for (int r = 0; r < 4; r++) {
      float o[4];
#pragma unroll
      for (int c = 0; c < 4; c++) o[c] = fmaxf(acc[r][c] + bb[c], 0.0f);
      *(float4*)&C[(size_t)(m0 + ty * 4 + r) * ldc + n0 + tx * 4] = *(float4*)&o[0];
    }
  } else {
    float cs[4] = {}, cq[4] = {};
#pragma unroll
    for (int r = 0; r < 4; r++) {
      float o[4];
#pragma unroll
      for (int c = 0; c < 4; c++) {
        float v = acc[r][c] + bb[c];
        o[c] = v;
        cs[c] += v;
        cq[c] += v * v;
      }
      *(float4*)&C[(size_t)(m0 + ty * 4 + r) * ldc + n0 + tx * 4] = *(float4*)&o[0];
    }
#pragma unroll
    for (int c = 0; c < 4; c++) {
      atomicAdd(&colsum[n0 + tx * 4 + c], cs[c]);
      atomicAdd(&colsumsq[n0 + tx * 4 + c], cq[c]);
    }
  }
}

// ---------------------------------------------------------------------------
// Whitening stats finalize: mean / 1/(std_ddof1 + 1e-5) for 3*128 columns.
// ---------------------------------------------------------------------------
__global__ void stats_kernel(const float* __restrict__ colsum,
                             const float* __restrict__ colsumsq,
                             float* __restrict__ meanv, float* __restrict__ invsd)
{
  int i = threadIdx.x;
  if (i < 3 * DOUT) {
    float mu  = colsum[i] / (float)NROWS;
    float var = (colsumsq[i] - (float)NROWS * mu * mu) / (float)(NROWS - 1);
    float sd  = sqrtf(fmaxf(var, 0.0f)) + 1e-5f;
    meanv[i] = mu;
    invsd[i] = 1.0f / sd;
  }
}

// ---------------------------------------------------------------------------
// Whiten + L2-normalize rows (in place, all 3 heads) + positive-pair dots.
// One block (128 threads) per row.
// ---------------------------------------------------------------------------
__global__ __launch_bounds__(128) void whiten_kernel(
    float* __restrict__ yB, float* __restrict__ yE, float* __restrict__ yF,
    const float* __restrict__ meanv, const float* __restrict__ invsd,
    float* __restrict__ pos)
{
  int row = blockIdx.x, t = threadIdx.x;
  size_t off = (size_t)row * DOUT + t;
  float vB = (yB[off] - meanv[t])            * invsd[t];
  float vE = (yE[off] - meanv[DOUT + t])     * invsd[DOUT + t];
  float vF = (yF[off] - meanv[2 * DOUT + t]) * invsd[2 * DOUT + t];

  __shared__ float red[6], red2[6];
  float nB = vB * vB, nE = vE * vE, nF = vF * vF;
#pragma unroll
  for (int o = 32; o > 0; o >>= 1) {
    nB += __shfl_down(nB, o, 64);
    nE += __shfl_down(nE, o, 64);
    nF += __shfl_down(nF, o, 64);
  }
  int lane = t & 63, wv = t >> 6;
  if (lane == 0) { red[wv * 3] = nB; red[wv * 3 + 1] = nE; red[wv * 3 + 2] = nF; }
  __syncthreads();
  float iB = 1.0f / fmaxf(sqrtf(red[0] + red[3]), 1e-12f);
  float iE = 1.0f / fmaxf(sqrtf(red[1] + red[4]), 1e-12f);
  float iF = 1.0f / fmaxf(sqrtf(red[2] + red[5]), 1e-12f);
  float zb = vB * iB, ze = vE * iE, zf = vF * iF;
  yB[off] = zb; yE[off] = ze; yF[off] = zf;

  float pBE = zb * ze, pBF = zb * zf, pEF = ze * zf;
#pragma unroll
  for (int o = 32; o > 0; o >>= 1) {
    pBE += __shfl_down(pBE, o, 64);
    pBF += __shfl_down(pBF, o, 64);
    pEF += __shfl_down(pEF, o, 64);
  }
  if (lane == 0) { red2[wv * 3] = pBE; red2[wv * 3 + 1] = pBF; red2[wv * 3 + 2] = pEF; }
  __syncthreads();
  if (t == 0) {
    pos[row]             = red2[0] + red2[3];
    pos[NROWS + row]     = red2[1] + red2[4];
    pos[2 * NROWS + row] = red2[2] + red2[5];
  }
}

// ---------------------------------------------------------------------------
// Exp-sum Gram: rowsum_i += sum_j exp(U_i . V_j) for 5 (U,V) combos.
// Tile 128x128, micro 8x8, BK=32. grid (64, 64, 5).
// ---------------------------------------------------------------------------
__global__ __launch_bounds__(256) void gram_kernel(
    const float* __restrict__ zB, const float* __restrict__ zE,
    const float* __restrict__ zF, float* __restrict__ rowsum)
{
  const float *U, *V;
  float* rs;
  switch (blockIdx.z) {
    case 0:  U = zB; V = zB; rs = rowsum;             break;
    case 1:  U = zE; V = zE; rs = rowsum + NROWS;     break;
    case 2:  U = zB; V = zE; rs = rowsum + 2 * NROWS; break;
    case 3:  U = zB; V = zF; rs = rowsum + 3 * NROWS; break;
    default: U = zE; V = zF; rs = rowsum + 4 * NROWS; break;
  }

  __shared__ __align__(16) float As[32][132];  // [k][m]
  __shared__ __align__(16) float Bs[32][132];  // [k][n]
  const int tid = threadIdx.x;
  const int tx = tid & 15, ty = tid >> 4;
  const int m0 = blockIdx.x * 128, n0 = blockIdx.y * 128;

  float acc[8][8] = {};

  for (int kk = 0; kk < DOUT; kk += 32) {
#pragma unroll
    for (int i = 0; i < 16; i++) {
      int e = i * 256 + tid;
      int k = e & 31, m = e >> 5;
      As[k][m] = U[(size_t)(m0 + m) * DOUT + kk + k];
      Bs[k][m] = V[(size_t)(n0 + m) * DOUT + kk + k];
    }
    __syncthreads();
#pragma unroll
    for (int k = 0; k < 32; k++) {
      float a[8], b[8];
      *(float4*)&a[0] = *(const float4*)&As[k][ty * 8];
      *(float4*)&a[4] = *(const float4*)&As[k][ty * 8 + 4];
      *(float4*)&b[0] = *(const float4*)&Bs[k][tx * 8];
      *(float4*)&b[4] = *(const float4*)&Bs[k][tx * 8 + 4];
#pragma unroll
      for (int r = 0; r < 8; r++)
#pragma unroll
        for (int c = 0; c < 8; c++)
          acc[r][c] = fmaf(a[r], b[c], acc[r][c]);
    }
    __syncthreads();
  }

  float rsm[8];
#pragma unroll
  for (int r = 0; r < 8; r++) {
    float s = 0.0f;
#pragma unroll
    for (int c = 0; c < 8; c++) s += __expf(acc[r][c]);
    rsm[r] = s;
  }
#pragma unroll
  for (int o = 8; o > 0; o >>= 1)
#pragma unroll
    for (int r = 0; r < 8; r++) rsm[r] += __shfl_down(rsm[r], o, 16);
  if (tx == 0) {
#pragma unroll
    for (int r = 0; r < 8; r++) atomicAdd(&rs[m0 + ty * 8 + r], rsm[r]);
  }
}

// ---------------------------------------------------------------------------
// Final loss. logits[i,i] masked to 0: self - e^{||z||^2} + e^0 = self+(1-e).
// loss = mean over rows+pairs of [log(self'+cross) - pos].
// ---------------------------------------------------------------------------
__global__ __launch_bounds__(1024) void loss_kernel(
    const float* __restrict__ rowsum, const float* __restrict__ pos,
    float* __restrict__ out)
{
  const float* sB  = rowsum;
  const float* sE  = rowsum + NROWS;
  const float* cBE = rowsum + 2 * NROWS;
  const float* cBF = rowsum + 3 * NROWS;
  const float* cEF = rowsum + 4 * NROWS;
  const float* pBE = pos;
  const float* pBF = pos + NROWS;
  const float* pEF = pos + 2 * NROWS;

  const float corr = 1.0f - expf(1.0f);  // remove masked self-logit, add exp(0)
  float local = 0.0f;
  for (int i = threadIdx.x; i < NROWS; i += 1024) {
    float selB = sB[i] + corr;
    float selE = sE[i] + corr;
    local += __logf(selB + cBE[i]) - pBE[i];
    local += __logf(selB + cBF[i]) - pBF[i];
    local += __logf(selE + cEF[i]) - pEF[i];
  }
  __shared__ float red[16];
#pragma unroll
  for (int o = 32; o > 0; o >>= 1) local += __shfl_down(local, o, 64);
  int lane = threadIdx.x & 63, wv = threadIdx.x >> 6;
  if (lane == 0) red[wv] = local;
  __syncthreads();
  if (threadIdx.x == 0) {
    float t = 0.0f;
#pragma unroll
    for (int w = 0; w < 16; w++) t += red[w];
    out[0] = t / (3.0f * (float)NROWS);
  }
}

// ---------------------------------------------------------------------------
extern "C" void kernel_launch(void* const* d_in, const int* in_sizes, int n_in,
                              void* d_out, int out_size, void* d_ws, size_t ws_size,
                              hipStream_t stream)
{
  const float* xs[3] = {(const float*)d_in[0], (const float*)d_in[1], (const float*)d_in[2]};
  const float* W1[3] = {(const float*)d_in[3], (const float*)d_in[7],  (const float*)d_in[11]};
  const float* b1[3] = {(const float*)d_in[4], (const float*)d_in[8],  (const float*)d_in[12]};
  const float* W2[3] = {(const float*)d_in[5], (const float*)d_in[9],  (const float*)d_in[13]};
  const float* b2[3] = {(const float*)d_in[6], (const float*)d_in[10], (const float*)d_in[14]};

  float* ws = (float*)d_ws;
  // workspace layout (floats):
  float* colsum   = ws;            // 384   [zeroed]
  float* colsumsq = ws + 384;      // 384   [zeroed]
  float* rowsum   = ws + 768;      // 5*8192 [zeroed]
  float* meanv    = ws + 41728;    // 384
  float* invsd    = ws + 42112;    // 384
  float* pos      = ws + 42496;    // 3*8192
  float* h        = ws + 67072;    // 8192*256 (reused across heads)
  float* y        = ws + 67072 + (size_t)NROWS * DHID;  // 3 * 8192*128
  // total = 5,309,952 floats = 21.2 MB

  // zero the atomic accumulators (ws is poisoned to 0xAA before each launch)
  hipMemsetAsync(ws, 0, 41728 * sizeof(float), stream);

  for (int m = 0; m < 3; m++) {
    float* ym = y + (size_t)m * NROWS * DOUT;
    mlp_gemm_kernel<<<dim3(128, 4), 256, 0, stream>>>(
        xs[m], DIN, DIN, W1[m], DHID, b1[m], h, DHID, 1, nullptr, nullptr);
    mlp_gemm_kernel<<<dim3(128, 2), 256, 0, stream>>>(
        h, DHID, DHID, W2[m], DOUT, b2[m], ym, DOUT, 0,
        colsum + m * DOUT, colsumsq + m * DOUT);
  }
  stats_kernel<<<1, 3 * DOUT, 0, stream>>>(colsum, colsumsq, meanv, invsd);
  whiten_kernel<<<NROWS, 128, 0, stream>>>(
      y, y + (size_t)NROWS * DOUT, y + 2 * (size_t)NROWS * DOUT, meanv, invsd, pos);
  gram_kernel<<<dim3(64, 64, 5), 256, 0, stream>>>(
      y, y + (size_t)NROWS * DOUT, y + 2 * (size_t)NROWS * DOUT, rowsum);
  loss_kernel<<<1, 1024, 0, stream>>>(rowsum, pos, (float*)d_out);
}

// Round 2
// 1174.333 us; speedup vs baseline: 1.8850x; 1.8850x over previous
//
#include <hip/hip_runtime.h>
#include <hip/hip_bf16.h>
#include <math.h>

#define NROWS 8192
#define DIN   512
#define DHID  256
#define DOUT  128

typedef unsigned short ushort_t;
typedef __attribute__((ext_vector_type(8))) short bf16x8;
typedef __attribute__((ext_vector_type(4))) float f32x4;

// ---------------------------------------------------------------------------
// Fused MLP GEMM: C = act(A @ W + bias), tile 64x64, micro 4x4, BK=32.
// relu=1 -> ReLU epilogue (GEMM1 -> h). relu=0 -> plain + per-column
// sum/sumsq atomics for the whitening stats (GEMM2 -> y).
// ---------------------------------------------------------------------------
__global__ __launch_bounds__(256) void mlp_gemm_kernel(
    const float* __restrict__ A, int lda, int K,
    const float* __restrict__ W, int ldw,
    const float* __restrict__ bias,
    float* __restrict__ C, int ldc,
    int relu, float* __restrict__ colsum, float* __restrict__ colsumsq)
{
  __shared__ __align__(16) float As[32][68];  // [k][m] transposed
  __shared__ __align__(16) float Bs[32][68];  // [k][n]
  const int tid = threadIdx.x;
  const int tx = tid & 15, ty = tid >> 4;
  const int m0 = blockIdx.x * 64, n0 = blockIdx.y * 64;

  float acc[4][4] = {};

  for (int kk = 0; kk < K; kk += 32) {
#pragma unroll
    for (int i = 0; i < 8; i++) {           // A tile: 64 rows x 32 k
      int e = i * 256 + tid;
      int k = e & 31, m = e >> 5;
      As[k][m] = A[(size_t)(m0 + m) * lda + kk + k];
    }
#pragma unroll
    for (int i = 0; i < 8; i++) {           // W tile: 32 k x 64 n (no transpose)
      int e = i * 256 + tid;
      int j = e & 63, k = e >> 6;
      Bs[k][j] = W[(size_t)(kk + k) * ldw + n0 + j];
    }
    __syncthreads();
#pragma unroll
    for (int k = 0; k < 32; k++) {
      float a[4], b[4];
      *(float4*)&a[0] = *(const float4*)&As[k][ty * 4];
      *(float4*)&b[0] = *(const float4*)&Bs[k][tx * 4];
#pragma unroll
      for (int r = 0; r < 4; r++)
#pragma unroll
        for (int c = 0; c < 4; c++)
          acc[r][c] = fmaf(a[r], b[c], acc[r][c]);
    }
    __syncthreads();
  }

  float bb[4];
  *(float4*)&bb[0] = *(const float4*)&bias[n0 + tx * 4];

  if (relu) {
#pragma unroll
    for (int r = 0; r < 4; r++) {
      float o[4];
#pragma unroll
      for (int c = 0; c < 4; c++) o[c] = fmaxf(acc[r][c] + bb[c], 0.0f);
      *(float4*)&C[(size_t)(m0 + ty * 4 + r) * ldc + n0 + tx * 4] = *(float4*)&o[0];
    }
  } else {
    float cs[4] = {}, cq[4] = {};
#pragma unroll
    for (int r = 0; r < 4; r++) {
      float o[4];
#pragma unroll
      for (int c = 0; c < 4; c++) {
        float v = acc[r][c] + bb[c];
        o[c] = v;
        cs[c] += v;
        cq[c] += v * v;
      }
      *(float4*)&C[(size_t)(m0 + ty * 4 + r) * ldc + n0 + tx * 4] = *(float4*)&o[0];
    }
#pragma unroll
    for (int c = 0; c < 4; c++) {
      atomicAdd(&colsum[n0 + tx * 4 + c], cs[c]);
      atomicAdd(&colsumsq[n0 + tx * 4 + c], cq[c]);
    }
  }
}

// ---------------------------------------------------------------------------
// Whitening stats finalize: mean / 1/(std_ddof1 + 1e-5) for 3*128 columns.
// ---------------------------------------------------------------------------
__global__ void stats_kernel(const float* __restrict__ colsum,
                             const float* __restrict__ colsumsq,
                             float* __restrict__ meanv, float* __restrict__ invsd)
{
  int i = threadIdx.x;
  if (i < 3 * DOUT) {
    float mu  = colsum[i] / (float)NROWS;
    float var = (colsumsq[i] - (float)NROWS * mu * mu) / (float)(NROWS - 1);
    float sd  = sqrtf(fmaxf(var, 0.0f)) + 1e-5f;
    meanv[i] = mu;
    invsd[i] = 1.0f / sd;
  }
}

// ---------------------------------------------------------------------------
// Whiten + L2-normalize rows + positive-pair dots (fp32) + bf16 z output.
// One block (128 threads) per row.
// ---------------------------------------------------------------------------
__global__ __launch_bounds__(128) void whiten_kernel(
    const float* __restrict__ yB, const float* __restrict__ yE,
    const float* __restrict__ yF,
    const float* __restrict__ meanv, const float* __restrict__ invsd,
    ushort_t* __restrict__ zbB, ushort_t* __restrict__ zbE,
    ushort_t* __restrict__ zbF,
    float* __restrict__ pos)
{
  int row = blockIdx.x, t = threadIdx.x;
  size_t off = (size_t)row * DOUT + t;
  float vB = (yB[off] - meanv[t])            * invsd[t];
  float vE = (yE[off] - meanv[DOUT + t])     * invsd[DOUT + t];
  float vF = (yF[off] - meanv[2 * DOUT + t]) * invsd[2 * DOUT + t];

  __shared__ float red[6], red2[6];
  float nB = vB * vB, nE = vE * vE, nF = vF * vF;
#pragma unroll
  for (int o = 32; o > 0; o >>= 1) {
    nB += __shfl_down(nB, o, 64);
    nE += __shfl_down(nE, o, 64);
    nF += __shfl_down(nF, o, 64);
  }
  int lane = t & 63, wv = t >> 6;
  if (lane == 0) { red[wv * 3] = nB; red[wv * 3 + 1] = nE; red[wv * 3 + 2] = nF; }
  __syncthreads();
  float iB = 1.0f / fmaxf(sqrtf(red[0] + red[3]), 1e-12f);
  float iE = 1.0f / fmaxf(sqrtf(red[1] + red[4]), 1e-12f);
  float iF = 1.0f / fmaxf(sqrtf(red[2] + red[5]), 1e-12f);
  float zb = vB * iB, ze = vE * iE, zf = vF * iF;

  __hip_bfloat16 hb = __float2bfloat16(zb);
  __hip_bfloat16 he = __float2bfloat16(ze);
  __hip_bfloat16 hf = __float2bfloat16(zf);
  zbB[off] = *(ushort_t*)&hb;
  zbE[off] = *(ushort_t*)&he;
  zbF[off] = *(ushort_t*)&hf;

  float pBE = zb * ze, pBF = zb * zf, pEF = ze * zf;
#pragma unroll
  for (int o = 32; o > 0; o >>= 1) {
    pBE += __shfl_down(pBE, o, 64);
    pBF += __shfl_down(pBF, o, 64);
    pEF += __shfl_down(pEF, o, 64);
  }
  if (lane == 0) { red2[wv * 3] = pBE; red2[wv * 3 + 1] = pBF; red2[wv * 3 + 2] = pEF; }
  __syncthreads();
  if (t == 0) {
    pos[row]             = red2[0] + red2[3];
    pos[NROWS + row]     = red2[1] + red2[4];
    pos[2 * NROWS + row] = red2[2] + red2[5];
  }
}

// ---------------------------------------------------------------------------
// Exp-sum Gram via bf16 MFMA: rowsum_i += sum_j exp(U_i . V_j), 5 combos.
// 128x128 tile / block, 4 waves in 2x2, each wave 4x4 tiles of 16x16x32.
// Fragments loaded DIRECTLY from global (row-major, contiguous k): no LDS.
// A-layout: A[m=lane&15][k=quad*8+j]; C/D: col=lane&15, row=quad*4+reg.
// ---------------------------------------------------------------------------
__global__ __launch_bounds__(256) void gram_mfma_kernel(
    const ushort_t* __restrict__ zB, const ushort_t* __restrict__ zE,
    const ushort_t* __restrict__ zF, float* __restrict__ rowsum)
{
  const ushort_t *U, *V;
  float* rs;
  switch (blockIdx.z) {
    case 0:  U = zB; V = zB; rs = rowsum;             break;
    case 1:  U = zE; V = zE; rs = rowsum + NROWS;     break;
    case 2:  U = zB; V = zE; rs = rowsum + 2 * NROWS; break;
    case 3:  U = zB; V = zF; rs = rowsum + 3 * NROWS; break;
    default: U = zE; V = zF; rs = rowsum + 4 * NROWS; break;
  }

  const int tid  = threadIdx.x;
  const int lane = tid & 63, wave = tid >> 6;
  const int wr = wave >> 1, wc = wave & 1;
  const int quad = lane >> 4, l16 = lane & 15;
  const int m0 = blockIdx.x * 128 + wr * 64;
  const int n0 = blockIdx.y * 128 + wc * 64;

  // lane's fragment base pointers (k = quad*8 + j, j contiguous)
  const ushort_t* ua = U + (size_t)(m0 + l16) * DOUT + quad * 8;
  const ushort_t* vb = V + (size_t)(n0 + l16) * DOUT + quad * 8;

  f32x4 acc[4][4] = {};     // [row-tile][col-tile]
  bf16x8 a[2][4], b[2][4];  // double-buffered fragments

#pragma unroll
  for (int rt = 0; rt < 4; rt++) {
    a[0][rt] = *(const bf16x8*)(ua + rt * 16 * DOUT);
    b[0][rt] = *(const bf16x8*)(vb + rt * 16 * DOUT);
  }

#pragma unroll
  for (int ki = 0; ki < 4; ki++) {
    const int cur = ki & 1;
    if (ki < 3) {
      const int koff = (ki + 1) * 32;
#pragma unroll
      for (int rt = 0; rt < 4; rt++) {
        a[cur ^ 1][rt] = *(const bf16x8*)(ua + rt * 16 * DOUT + koff);
        b[cur ^ 1][rt] = *(const bf16x8*)(vb + rt * 16 * DOUT + koff);
      }
    }
#pragma unroll
    for (int rt = 0; rt < 4; rt++)
#pragma unroll
      for (int ct = 0; ct < 4; ct++)
        acc[rt][ct] = __builtin_amdgcn_mfma_f32_16x16x32_bf16(
            a[cur][rt], b[cur][ct], acc[rt][ct], 0, 0, 0);
  }

  // Epilogue: exp + row-sum. Row of acc element = rt*16 + quad*4 + reg,
  // col = ct*16 + l16. Sum over cols: per-lane over ct, then shfl over l16.
#pragma unroll
  for (int rt = 0; rt < 4; rt++) {
#pragma unroll
    for (int reg = 0; reg < 4; reg++) {
      float s = __expf(acc[rt][0][reg]) + __expf(acc[rt][1][reg]) +
                __expf(acc[rt][2][reg]) + __expf(acc[rt][3][reg]);
      s += __shfl_xor(s, 1, 64);
      s += __shfl_xor(s, 2, 64);
      s += __shfl_xor(s, 4, 64);
      s += __shfl_xor(s, 8, 64);
      if (l16 == 0)
        atomicAdd(&rs[m0 + rt * 16 + quad * 4 + reg], s);
    }
  }
}

// ---------------------------------------------------------------------------
// Final loss. logits[i,i] masked to 0: self - e^{~1} + e^0 ~= self + (1-e).
// ---------------------------------------------------------------------------
__global__ __launch_bounds__(1024) void loss_kernel(
    const float* __restrict__ rowsum, const float* __restrict__ pos,
    float* __restrict__ out)
{
  const float* sB  = rowsum;
  const float* sE  = rowsum + NROWS;
  const float* cBE = rowsum + 2 * NROWS;
  const float* cBF = rowsum + 3 * NROWS;
  const float* cEF = rowsum + 4 * NROWS;
  const float* pBE = pos;
  const float* pBF = pos + NROWS;
  const float* pEF = pos + 2 * NROWS;

  const float corr = 1.0f - expf(1.0f);  // remove masked self-logit, add exp(0)
  float local = 0.0f;
  for (int i = threadIdx.x; i < NROWS; i += 1024) {
    float selB = sB[i] + corr;
    float selE = sE[i] + corr;
    local += __logf(selB + cBE[i]) - pBE[i];
    local += __logf(selB + cBF[i]) - pBF[i];
    local += __logf(selE + cEF[i]) - pEF[i];
  }
  __shared__ float red[16];
#pragma unroll
  for (int o = 32; o > 0; o >>= 1) local += __shfl_down(local, o, 64);
  int lane = threadIdx.x & 63, wv = threadIdx.x >> 6;
  if (lane == 0) red[wv] = local;
  __syncthreads();
  if (threadIdx.x == 0) {
    float t = 0.0f;
#pragma unroll
    for (int w = 0; w < 16; w++) t += red[w];
    out[0] = t / (3.0f * (float)NROWS);
  }
}

// ---------------------------------------------------------------------------
extern "C" void kernel_launch(void* const* d_in, const int* in_sizes, int n_in,
                              void* d_out, int out_size, void* d_ws, size_t ws_size,
                              hipStream_t stream)
{
  const float* xs[3] = {(const float*)d_in[0], (const float*)d_in[1], (const float*)d_in[2]};
  const float* W1[3] = {(const float*)d_in[3], (const float*)d_in[7],  (const float*)d_in[11]};
  const float* b1[3] = {(const float*)d_in[4], (const float*)d_in[8],  (const float*)d_in[12]};
  const float* W2[3] = {(const float*)d_in[5], (const float*)d_in[9],  (const float*)d_in[13]};
  const float* b2[3] = {(const float*)d_in[6], (const float*)d_in[10], (const float*)d_in[14]};

  float* ws = (float*)d_ws;
  // workspace layout (floats):
  float* colsum   = ws;            // 384   [zeroed]
  float* colsumsq = ws + 384;      // 384   [zeroed]
  float* rowsum   = ws + 768;      // 5*8192 [zeroed]
  float* meanv    = ws + 41728;    // 384
  float* invsd    = ws + 42112;    // 384
  float* pos      = ws + 42496;    // 3*8192
  float* h        = ws + 67072;    // 8192*256 fp32 (reused: bf16 z after MLP)
  float* y        = ws + 67072 + (size_t)NROWS * DHID;  // 3 * 8192*128 fp32
  // bf16 z buffers live in h's space (h is dead after the MLP phase):
  ushort_t* zbB = (ushort_t*)h;                       // 8192*128 bf16 = 2 MB
  ushort_t* zbE = zbB + (size_t)NROWS * DOUT;
  ushort_t* zbF = zbE + (size_t)NROWS * DOUT;         // total 6 MB <= 8 MB (h)

  // zero the atomic accumulators (ws is poisoned to 0xAA before each launch)
  hipMemsetAsync(ws, 0, 41728 * sizeof(float), stream);

  for (int m = 0; m < 3; m++) {
    float* ym = y + (size_t)m * NROWS * DOUT;
    mlp_gemm_kernel<<<dim3(128, 4), 256, 0, stream>>>(
        xs[m], DIN, DIN, W1[m], DHID, b1[m], h, DHID, 1, nullptr, nullptr);
    mlp_gemm_kernel<<<dim3(128, 2), 256, 0, stream>>>(
        h, DHID, DHID, W2[m], DOUT, b2[m], ym, DOUT, 0,
        colsum + m * DOUT, colsumsq + m * DOUT);
  }
  stats_kernel<<<1, 3 * DOUT, 0, stream>>>(colsum, colsumsq, meanv, invsd);
  whiten_kernel<<<NROWS, 128, 0, stream>>>(
      y, y + (size_t)NROWS * DOUT, y + 2 * (size_t)NROWS * DOUT,
      meanv, invsd, zbB, zbE, zbF, pos);
  gram_mfma_kernel<<<dim3(64, 64, 5), 256, 0, stream>>>(zbB, zbE, zbF, rowsum);
  loss_kernel<<<1, 1024, 0, stream>>>(rowsum, pos, (float*)d_out);
}

// Round 3
// 401.121 us; speedup vs baseline: 5.5185x; 2.9276x over previous
//
#include <hip/hip_runtime.h>
#include <hip/hip_bf16.h>
#include <math.h>

#define NROWS 8192
#define DIN   512
#define DHID  256
#define DOUT  128
#define LOG2E 1.4426950408889634f

typedef unsigned short ushort_t;
typedef __attribute__((ext_vector_type(8))) short bf16x8;
typedef __attribute__((ext_vector_type(4))) float f32x4;

#if defined(__has_builtin)
#  if __has_builtin(__builtin_amdgcn_exp2f)
#    define FAST_EXP2(x) __builtin_amdgcn_exp2f(x)
#  else
#    define FAST_EXP2(x) exp2f(x)
#  endif
#else
#  define FAST_EXP2(x) exp2f(x)
#endif

__device__ __forceinline__ short f2bf(float x) {
  __hip_bfloat16 h = __float2bfloat16(x);
  return *(short*)&h;
}

// ---------------------------------------------------------------------------
// fp32 -> bf16 convert, 8 elems/thread (x: 8192x512).
// ---------------------------------------------------------------------------
__global__ __launch_bounds__(256) void convert_x_kernel(
    const float* __restrict__ src, ushort_t* __restrict__ dst)
{
  int idx = (blockIdx.x * 256 + threadIdx.x) * 8;
  float4 f0 = *(const float4*)(src + idx);
  float4 f1 = *(const float4*)(src + idx + 4);
  bf16x8 o;
  o[0] = f2bf(f0.x); o[1] = f2bf(f0.y); o[2] = f2bf(f0.z); o[3] = f2bf(f0.w);
  o[4] = f2bf(f1.x); o[5] = f2bf(f1.y); o[6] = f2bf(f1.z); o[7] = f2bf(f1.w);
  *(bf16x8*)(dst + idx) = o;
}

// ---------------------------------------------------------------------------
// Transpose W1 (512x256) -> w1t (256x512) and W2 (256x128) -> w2t (128x256),
// fp32 -> bf16. grid 640x256 covers 131072 + 32768 elems.
// ---------------------------------------------------------------------------
__global__ __launch_bounds__(256) void prep_w_kernel(
    const float* __restrict__ W1, const float* __restrict__ W2,
    ushort_t* __restrict__ w1t, ushort_t* __restrict__ w2t)
{
  int idx = blockIdx.x * 256 + threadIdx.x;
  if (idx < DHID * DIN) {
    int n = idx >> 9, k = idx & (DIN - 1);
    w1t[idx] = f2bf(W1[(size_t)k * DHID + n]);
  } else {
    int j = idx - DHID * DIN;
    int n = j >> 8, k = j & (DHID - 1);
    w2t[j] = f2bf(W2[(size_t)k * DOUT + n]);
  }
}

// ---------------------------------------------------------------------------
// GEMM1: H = relu(A @ W1 + b1), bf16 MFMA, direct-global fragments, no LDS.
// A: 8192x512 bf16 (k contig). Bt = W1^T: 256x512 bf16 (k contig).
// Block tile 64(M) x 128(N), 4 waves 2x2 (wave 32x64). KI = 16.
// ---------------------------------------------------------------------------
__global__ __launch_bounds__(256) void gemm1_kernel(
    const ushort_t* __restrict__ A, const ushort_t* __restrict__ Bt,
    const float* __restrict__ bias, ushort_t* __restrict__ H)
{
  const int tid = threadIdx.x, lane = tid & 63, wave = tid >> 6;
  const int wr = wave >> 1, wc = wave & 1, quad = lane >> 4, l16 = lane & 15;
  const int m0 = blockIdx.x * 64 + wr * 32;
  const int n0 = blockIdx.y * 128 + wc * 64;
  const ushort_t* pa = A + (size_t)(m0 + l16) * DIN + quad * 8;
  const ushort_t* pb = Bt + (size_t)(n0 + l16) * DIN + quad * 8;

  f32x4 acc[2][4] = {};
  bf16x8 a[2][2], b[2][4];
#pragma unroll
  for (int rt = 0; rt < 2; rt++) a[0][rt] = *(const bf16x8*)(pa + rt * 16 * DIN);
#pragma unroll
  for (int ct = 0; ct < 4; ct++) b[0][ct] = *(const bf16x8*)(pb + ct * 16 * DIN);

#pragma unroll
  for (int ki = 0; ki < 16; ki++) {
    const int cur = ki & 1;
    if (ki < 15) {
      const int off = (ki + 1) * 32;
#pragma unroll
      for (int rt = 0; rt < 2; rt++)
        a[cur ^ 1][rt] = *(const bf16x8*)(pa + rt * 16 * DIN + off);
#pragma unroll
      for (int ct = 0; ct < 4; ct++)
        b[cur ^ 1][ct] = *(const bf16x8*)(pb + ct * 16 * DIN + off);
    }
#pragma unroll
    for (int rt = 0; rt < 2; rt++)
#pragma unroll
      for (int ct = 0; ct < 4; ct++)
        acc[rt][ct] = __builtin_amdgcn_mfma_f32_16x16x32_bf16(
            a[cur][rt], b[cur][ct], acc[rt][ct], 0, 0, 0);
  }

  float bb[4];
#pragma unroll
  for (int ct = 0; ct < 4; ct++) bb[ct] = bias[n0 + ct * 16 + l16];
#pragma unroll
  for (int rt = 0; rt < 2; rt++)
#pragma unroll
    for (int ct = 0; ct < 4; ct++)
#pragma unroll
      for (int reg = 0; reg < 4; reg++) {
        float v = fmaxf(acc[rt][ct][reg] + bb[ct], 0.0f);
        H[(size_t)(m0 + rt * 16 + quad * 4 + reg) * DHID + n0 + ct * 16 + l16] =
            (ushort_t)f2bf(v);
      }
}

// ---------------------------------------------------------------------------
// GEMM2: Y = H @ W2 + b2 (fp32 out) + per-column sum/sumsq atomics.
// H: 8192x256 bf16. Bt = W2^T: 128x256 bf16. Tile 64x128, KI = 8.
// ---------------------------------------------------------------------------
__global__ __launch_bounds__(256) void gemm2_kernel(
    const ushort_t* __restrict__ A, const ushort_t* __restrict__ Bt,
    const float* __restrict__ bias, float* __restrict__ Y,
    float* __restrict__ colsum, float* __restrict__ colsumsq)
{
  const int tid = threadIdx.x, lane = tid & 63, wave = tid >> 6;
  const int wr = wave >> 1, wc = wave & 1, quad = lane >> 4, l16 = lane & 15;
  const int m0 = blockIdx.x * 64 + wr * 32;
  const int n0 = wc * 64;
  const ushort_t* pa = A + (size_t)(m0 + l16) * DHID + quad * 8;
  const ushort_t* pb = Bt + (size_t)(n0 + l16) * DHID + quad * 8;

  f32x4 acc[2][4] = {};
  bf16x8 a[2][2], b[2][4];
#pragma unroll
  for (int rt = 0; rt < 2; rt++) a[0][rt] = *(const bf16x8*)(pa + rt * 16 * DHID);
#pragma unroll
  for (int ct = 0; ct < 4; ct++) b[0][ct] = *(const bf16x8*)(pb + ct * 16 * DHID);

#pragma unroll
  for (int ki = 0; ki < 8; ki++) {
    const int cur = ki & 1;
    if (ki < 7) {
      const int off = (ki + 1) * 32;
#pragma unroll
      for (int rt = 0; rt < 2; rt++)
        a[cur ^ 1][rt] = *(const bf16x8*)(pa + rt * 16 * DHID + off);
#pragma unroll
      for (int ct = 0; ct < 4; ct++)
        b[cur ^ 1][ct] = *(const bf16x8*)(pb + ct * 16 * DHID + off);
    }
#pragma unroll
    for (int rt = 0; rt < 2; rt++)
#pragma unroll
      for (int ct = 0; ct < 4; ct++)
        acc[rt][ct] = __builtin_amdgcn_mfma_f32_16x16x32_bf16(
            a[cur][rt], b[cur][ct], acc[rt][ct], 0, 0, 0);
  }

  float bb[4];
#pragma unroll
  for (int ct = 0; ct < 4; ct++) bb[ct] = bias[n0 + ct * 16 + l16];
#pragma unroll
  for (int ct = 0; ct < 4; ct++) {
    float cs = 0.0f, cq = 0.0f;
#pragma unroll
    for (int rt = 0; rt < 2; rt++)
#pragma unroll
      for (int reg = 0; reg < 4; reg++) {
        float v = acc[rt][ct][reg] + bb[ct];
        Y[(size_t)(m0 + rt * 16 + quad * 4 + reg) * DOUT + n0 + ct * 16 + l16] = v;
        cs += v; cq += v * v;
      }
    cs += __shfl_xor(cs, 16, 64); cs += __shfl_xor(cs, 32, 64);
    cq += __shfl_xor(cq, 16, 64); cq += __shfl_xor(cq, 32, 64);
    if (lane < 16) {
      atomicAdd(&colsum[n0 + ct * 16 + l16], cs);
      atomicAdd(&colsumsq[n0 + ct * 16 + l16], cq);
    }
  }
}

// ---------------------------------------------------------------------------
// Whitening stats finalize.
// ---------------------------------------------------------------------------
__global__ void stats_kernel(const float* __restrict__ colsum,
                             const float* __restrict__ colsumsq,
                             float* __restrict__ meanv, float* __restrict__ invsd)
{
  int i = threadIdx.x;
  if (i < 3 * DOUT) {
    float mu  = colsum[i] / (float)NROWS;
    float var = (colsumsq[i] - (float)NROWS * mu * mu) / (float)(NROWS - 1);
    float sd  = sqrtf(fmaxf(var, 0.0f)) + 1e-5f;
    meanv[i] = mu;
    invsd[i] = 1.0f / sd;
  }
}

// ---------------------------------------------------------------------------
// Whiten + L2-normalize + pos dots (fp32) + bf16 z (plain V + log2e-scaled U).
// ---------------------------------------------------------------------------
__global__ __launch_bounds__(128) void whiten_kernel(
    const float* __restrict__ yB, const float* __restrict__ yE,
    const float* __restrict__ yF,
    const float* __restrict__ meanv, const float* __restrict__ invsd,
    ushort_t* __restrict__ zB, ushort_t* __restrict__ zE,
    ushort_t* __restrict__ zF,
    ushort_t* __restrict__ zBs, ushort_t* __restrict__ zEs,
    float* __restrict__ pos)
{
  int row = blockIdx.x, t = threadIdx.x;
  size_t off = (size_t)row * DOUT + t;
  float vB = (yB[off] - meanv[t])            * invsd[t];
  float vE = (yE[off] - meanv[DOUT + t])     * invsd[DOUT + t];
  float vF = (yF[off] - meanv[2 * DOUT + t]) * invsd[2 * DOUT + t];

  __shared__ float red[6], red2[6];
  float nB = vB * vB, nE = vE * vE, nF = vF * vF;
#pragma unroll
  for (int o = 32; o > 0; o >>= 1) {
    nB += __shfl_down(nB, o, 64);
    nE += __shfl_down(nE, o, 64);
    nF += __shfl_down(nF, o, 64);
  }
  int lane = t & 63, wv = t >> 6;
  if (lane == 0) { red[wv * 3] = nB; red[wv * 3 + 1] = nE; red[wv * 3 + 2] = nF; }
  __syncthreads();
  float iB = 1.0f / fmaxf(sqrtf(red[0] + red[3]), 1e-12f);
  float iE = 1.0f / fmaxf(sqrtf(red[1] + red[4]), 1e-12f);
  float iF = 1.0f / fmaxf(sqrtf(red[2] + red[5]), 1e-12f);
  float zb = vB * iB, ze = vE * iE, zf = vF * iF;

  zB[off]  = (ushort_t)f2bf(zb);
  zE[off]  = (ushort_t)f2bf(ze);
  zF[off]  = (ushort_t)f2bf(zf);
  zBs[off] = (ushort_t)f2bf(zb * LOG2E);
  zEs[off] = (ushort_t)f2bf(ze * LOG2E);

  float pBE = zb * ze, pBF = zb * zf, pEF = ze * zf;
#pragma unroll
  for (int o = 32; o > 0; o >>= 1) {
    pBE += __shfl_down(pBE, o, 64);
    pBF += __shfl_down(pBF, o, 64);
    pEF += __shfl_down(pEF, o, 64);
  }
  if (lane == 0) { red2[wv * 3] = pBE; red2[wv * 3 + 1] = pBF; red2[wv * 3 + 2] = pEF; }
  __syncthreads();
  if (t == 0) {
    pos[row]             = red2[0] + red2[3];
    pos[NROWS + row]     = red2[1] + red2[4];
    pos[2 * NROWS + row] = red2[2] + red2[5];
  }
}

// ---------------------------------------------------------------------------
// Gram v2: rowsum_i += sum_j exp2(Us_i . V_j). U pre-scaled by log2e.
// Grid (64 m-tiles, 4 n-chunks, 5 combos). Block = 128 rows x 2048 cols.
// Waves 2x2 over 128x128 working tile; 16 n-tiles looped; A frags cached in
// regs; rowsum accumulated in regs; one cross-lane reduce + atomic per block.
// ---------------------------------------------------------------------------
__global__ __launch_bounds__(256) void gram_mfma_kernel(
    const ushort_t* __restrict__ zB, const ushort_t* __restrict__ zE,
    const ushort_t* __restrict__ zF,
    const ushort_t* __restrict__ zBs, const ushort_t* __restrict__ zEs,
    float* __restrict__ rowsum)
{
  const ushort_t *U, *V;
  float* rs;
  switch (blockIdx.z) {
    case 0:  U = zBs; V = zB; rs = rowsum;             break;
    case 1:  U = zEs; V = zE; rs = rowsum + NROWS;     break;
    case 2:  U = zBs; V = zE; rs = rowsum + 2 * NROWS; break;
    case 3:  U = zBs; V = zF; rs = rowsum + 3 * NROWS; break;
    default: U = zEs; V = zF; rs = rowsum + 4 * NROWS; break;
  }

  const int tid = threadIdx.x, lane = tid & 63, wave = tid >> 6;
  const int wr = wave >> 1, wc = wave & 1, quad = lane >> 4, l16 = lane & 15;
  const int m0 = blockIdx.x * 128 + wr * 64;
  const int nbase = blockIdx.y * 2048 + wc * 64;

  // cache all A fragments for this wave's 64 rows (16 x bf16x8 = 64 VGPR)
  const ushort_t* ua = U + (size_t)(m0 + l16) * DOUT + quad * 8;
  bf16x8 a[4][4];
#pragma unroll
  for (int rt = 0; rt < 4; rt++)
#pragma unroll
    for (int ki = 0; ki < 4; ki++)
      a[rt][ki] = *(const bf16x8*)(ua + rt * 16 * DOUT + ki * 32);

  float rsum[4][4] = {};  // [rt][reg]
  const f32x4 zero = {0.0f, 0.0f, 0.0f, 0.0f};

  for (int nt = 0; nt < 16; nt++) {
    const ushort_t* vb = V + (size_t)(nbase + nt * 128 + l16) * DOUT + quad * 8;
    f32x4 acc[4][4];
    bf16x8 b[4];
#pragma unroll
    for (int ct = 0; ct < 4; ct++) b[ct] = *(const bf16x8*)(vb + ct * 16 * DOUT);
#pragma unroll
    for (int rt = 0; rt < 4; rt++)
#pragma unroll
      for (int ct = 0; ct < 4; ct++)
        acc[rt][ct] = __builtin_amdgcn_mfma_f32_16x16x32_bf16(
            a[rt][0], b[ct], zero, 0, 0, 0);
#pragma unroll
    for (int ki = 1; ki < 4; ki++) {
#pragma unroll
      for (int ct = 0; ct < 4; ct++)
        b[ct] = *(const bf16x8*)(vb + ct * 16 * DOUT + ki * 32);
#pragma unroll
      for (int rt = 0; rt < 4; rt++)
#pragma unroll
        for (int ct = 0; ct < 4; ct++)
          acc[rt][ct] = __builtin_amdgcn_mfma_f32_16x16x32_bf16(
              a[rt][ki], b[ct], acc[rt][ct], 0, 0, 0);
    }
    // exp2 + in-register row accumulation (no cross-lane here)
#pragma unroll
    for (int rt = 0; rt < 4; rt++)
#pragma unroll
      for (int reg = 0; reg < 4; reg++)
        rsum[rt][reg] += FAST_EXP2(acc[rt][0][reg]) + FAST_EXP2(acc[rt][1][reg]) +
                         FAST_EXP2(acc[rt][2][reg]) + FAST_EXP2(acc[rt][3][reg]);
  }

  // one cross-lane reduction over l16 + one atomic per row per block
#pragma unroll
  for (int rt = 0; rt < 4; rt++)
#pragma unroll
    for (int reg = 0; reg < 4; reg++) {
      float s = rsum[rt][reg];
      s += __shfl_xor(s, 1, 64);
      s += __shfl_xor(s, 2, 64);
      s += __shfl_xor(s, 4, 64);
      s += __shfl_xor(s, 8, 64);
      if (l16 == 0)
        atomicAdd(&rs[m0 + rt * 16 + quad * 4 + reg], s);
    }
}

// ---------------------------------------------------------------------------
// Final loss. logits[i,i] masked to 0: self + (1 - e).
// ---------------------------------------------------------------------------
__global__ __launch_bounds__(1024) void loss_kernel(
    const float* __restrict__ rowsum, const float* __restrict__ pos,
    float* __restrict__ out)
{
  const float* sB  = rowsum;
  const float* sE  = rowsum + NROWS;
  const float* cBE = rowsum + 2 * NROWS;
  const float* cBF = rowsum + 3 * NROWS;
  const float* cEF = rowsum + 4 * NROWS;
  const float* pBE = pos;
  const float* pBF = pos + NROWS;
  const float* pEF = pos + 2 * NROWS;

  const float corr = 1.0f - expf(1.0f);
  float local = 0.0f;
  for (int i = threadIdx.x; i < NROWS; i += 1024) {
    float selB = sB[i] + corr;
    float selE = sE[i] + corr;
    local += __logf(selB + cBE[i]) - pBE[i];
    local += __logf(selB + cBF[i]) - pBF[i];
    local += __logf(selE + cEF[i]) - pEF[i];
  }
  __shared__ float red[16];
#pragma unroll
  for (int o = 32; o > 0; o >>= 1) local += __shfl_down(local, o, 64);
  int lane = threadIdx.x & 63, wv = threadIdx.x >> 6;
  if (lane == 0) red[wv] = local;
  __syncthreads();
  if (threadIdx.x == 0) {
    float t = 0.0f;
#pragma unroll
    for (int w = 0; w < 16; w++) t += red[w];
    out[0] = t / (3.0f * (float)NROWS);
  }
}

// ---------------------------------------------------------------------------
extern "C" void kernel_launch(void* const* d_in, const int* in_sizes, int n_in,
                              void* d_out, int out_size, void* d_ws, size_t ws_size,
                              hipStream_t stream)
{
  const float* xs[3] = {(const float*)d_in[0], (const float*)d_in[1], (const float*)d_in[2]};
  const float* W1[3] = {(const float*)d_in[3], (const float*)d_in[7],  (const float*)d_in[11]};
  const float* b1[3] = {(const float*)d_in[4], (const float*)d_in[8],  (const float*)d_in[12]};
  const float* W2[3] = {(const float*)d_in[5], (const float*)d_in[9],  (const float*)d_in[13]};
  const float* b2[3] = {(const float*)d_in[6], (const float*)d_in[10], (const float*)d_in[14]};

  float* ws = (float*)d_ws;
  // workspace layout (float offsets):
  float* colsum   = ws;            // 384   [zeroed]
  float* colsumsq = ws + 384;      // 384   [zeroed]
  float* rowsum   = ws + 768;      // 5*8192 [zeroed]
  float* meanv    = ws + 41728;    // 384
  float* invsd    = ws + 42112;    // 384
  float* pos      = ws + 42496;    // 3*8192
  // MLP-phase buffers (ushort_t views share float space):
  ushort_t* xb  = (ushort_t*)(ws + 67072);    // 8192*512 bf16 = 2,097,152 floats
  ushort_t* w1t = (ushort_t*)(ws + 2164224);  // 256*512 bf16 = 65,536 floats
  ushort_t* w2t = (ushort_t*)(ws + 2229760);  // 128*256 bf16 = 16,384 floats
  ushort_t* h   = (ushort_t*)(ws + 2246144);  // 8192*256 bf16 = 1,048,576 floats
  float*    y   = ws + 3294720;               // 3 * 8192*128 fp32 = 3,145,728 floats
  // z buffers overlay the (dead after MLP phase) xb/w1t/w2t/h region:
  ushort_t* zB  = (ushort_t*)(ws + 67072);    // each 8192*128 bf16 = 524,288 floats
  ushort_t* zE  = zB  + (size_t)NROWS * DOUT;
  ushort_t* zF  = zE  + (size_t)NROWS * DOUT;
  ushort_t* zBs = zF  + (size_t)NROWS * DOUT;
  ushort_t* zEs = zBs + (size_t)NROWS * DOUT;
  // total ws usage: 6,440,448 floats = 25.8 MB

  hipMemsetAsync(ws, 0, 41728 * sizeof(float), stream);

  for (int m = 0; m < 3; m++) {
    float* ym = y + (size_t)m * NROWS * DOUT;
    convert_x_kernel<<<2048, 256, 0, stream>>>(xs[m], xb);
    prep_w_kernel<<<640, 256, 0, stream>>>(W1[m], W2[m], w1t, w2t);
    gemm1_kernel<<<dim3(128, 2), 256, 0, stream>>>(xb, w1t, b1[m], h);
    gemm2_kernel<<<dim3(128, 1), 256, 0, stream>>>(
        h, w2t, b2[m], ym, colsum + m * DOUT, colsumsq + m * DOUT);
  }
  stats_kernel<<<1, 3 * DOUT, 0, stream>>>(colsum, colsumsq, meanv, invsd);
  whiten_kernel<<<NROWS, 128, 0, stream>>>(
      y, y + (size_t)NROWS * DOUT, y + 2 * (size_t)NROWS * DOUT,
      meanv, invsd, zB, zE, zF, zBs, zEs, pos);
  gram_mfma_kernel<<<dim3(64, 4, 5), 256, 0, stream>>>(zB, zE, zF, zBs, zEs, rowsum);
  loss_kernel<<<1, 1024, 0, stream>>>(rowsum, pos, (float*)d_out);
}